// Round 1
// baseline (427.264 us; speedup 1.0000x reference)
//
#include <hip/hip_runtime.h>

// Problem constants (fixed by reference): B=4, S=2048, DIN=4096, DOUT=4096
#define GM 8192   // M = B*S
#define GN 4096   // N = DOUT
#define GK 4096   // K = DIN

#define BM 128
#define BN 128
#define BK 64     // bytes of K per tile (i8)

using int4v = __attribute__((ext_vector_type(4))) int;

// ---------------- quantization ----------------
// x_int8 = (int)(x * input_scale)  -- trunc toward zero, like astype(int32)
__global__ __launch_bounds__(256) void quant_x_k(const float4* __restrict__ x,
                                                 unsigned int* __restrict__ xq,
                                                 const float* __restrict__ iscale,
                                                 int n4) {
    int i = blockIdx.x * blockDim.x + threadIdx.x;
    if (i >= n4) return;
    float s = *iscale;
    float4 v = x[i];
    int q0 = (int)(v.x * s);
    int q1 = (int)(v.y * s);
    int q2 = (int)(v.z * s);
    int q3 = (int)(v.w * s);
    unsigned int packed = (unsigned int)(q0 & 0xff)
                        | ((unsigned int)(q1 & 0xff) << 8)
                        | ((unsigned int)(q2 & 0xff) << 16)
                        | ((unsigned int)(q3 & 0xff) << 24);
    xq[i] = packed;
}

// w_int8 = round_half_even(w * wscale[row]) -- rintf under default RNE
__global__ __launch_bounds__(256) void quant_w_k(const float4* __restrict__ w,
                                                 unsigned int* __restrict__ wq,
                                                 const float* __restrict__ wscale,
                                                 int n4) {
    int i = blockIdx.x * blockDim.x + threadIdx.x;
    if (i >= n4) return;
    int row = i >> 10;              // 4096 floats per row / 4 per float4
    float s = wscale[row];
    float4 v = w[i];
    int q0 = (int)rintf(v.x * s);
    int q1 = (int)rintf(v.y * s);
    int q2 = (int)rintf(v.z * s);
    int q3 = (int)rintf(v.w * s);
    unsigned int packed = (unsigned int)(q0 & 0xff)
                        | ((unsigned int)(q1 & 0xff) << 8)
                        | ((unsigned int)(q2 & 0xff) << 16)
                        | ((unsigned int)(q3 & 0xff) << 24);
    wq[i] = packed;
}

// ---------------- int8 GEMM (m97-ladder structure) ----------------
// A: M x K int8 row-major (x quantized), B: N x K int8 row-major (weight
// quantized; weight is stored [DOUT, DIN] so it is already B^T / K-contiguous).
// C[m][n] = (float(acc_i32) + bias[n]) * (1 / (wscale[n]*iscale))
__global__ __launch_bounds__(256) void qlinear_gemm_i8(
    const signed char* __restrict__ Aq,
    const signed char* __restrict__ Bq,
    const float* __restrict__ bias,
    const float* __restrict__ wscale,
    const float* __restrict__ iscale,
    float* __restrict__ C) {
    __shared__ signed char As[BM * BK];   // 8 KiB
    __shared__ signed char Bs[BN * BK];   // 8 KiB

    const int tid  = threadIdx.x;
    const int wave = tid >> 6;
    const int lane = tid & 63;
    const int m0 = blockIdx.x * BM;
    const int n0 = blockIdx.y * BN;
    // wave computes a 64x64 subtile (4x4 of 16x16)
    const int wm = (wave >> 1) * 64;
    const int wn = (wave & 1) * 64;

    int4v acc[4][4];
#pragma unroll
    for (int i = 0; i < 4; ++i)
#pragma unroll
        for (int j = 0; j < 4; ++j)
            acc[i][j] = int4v{0, 0, 0, 0};

    // --- staging assignment: per K-iter each tile is 8 KiB = 8 wave-segments
    // of 1 KiB (16 rows x 64 B). wave w stages segments {2w, 2w+1} of A and B.
    // lane l -> row_in_seg = l>>2, byte offset = (l&3)*16.
    // LDS dest = wave-uniform base + lane*16 (global_load_lds constraint).
    const int seg = wave * 2;
    const int rA = m0 + seg * 16 + (lane >> 2);
    const int rB = n0 + seg * 16 + (lane >> 2);
    const signed char* gA0 = Aq + (size_t)rA * GK + (lane & 3) * 16;
    const signed char* gA1 = gA0 + (size_t)16 * GK;
    const signed char* gB0 = Bq + (size_t)rB * GK + (lane & 3) * 16;
    const signed char* gB1 = gB0 + (size_t)16 * GK;
    signed char* lA0 = As + seg * 1024 + lane * 16;
    signed char* lA1 = lA0 + 1024;
    signed char* lB0 = Bs + seg * 1024 + lane * 16;
    signed char* lB1 = lB0 + 1024;

    // --- LDS fragment read addresses (A-operand layout for 16x16x64 i8:
    // elem[m = lane&15][k = (lane>>4)*16 + j], j=0..15 -> one ds_read_b128)
    const int kgrp = (lane >> 4) * 16;
    const signed char* fA = As + (wm + (lane & 15)) * BK + kgrp;
    const signed char* fB = Bs + (wn + (lane & 15)) * BK + kgrp;

#define GLL16(g, l)                                                     \
    __builtin_amdgcn_global_load_lds(                                   \
        (__attribute__((address_space(1))) void*)(void*)(g),            \
        (__attribute__((address_space(3))) void*)(l), 16, 0, 0)

    for (int k0 = 0; k0 < GK; k0 += BK) {
        GLL16(gA0 + k0, lA0);
        GLL16(gA1 + k0, lA1);
        GLL16(gB0 + k0, lB0);
        GLL16(gB1 + k0, lB1);
        __syncthreads();   // compiler emits vmcnt(0) drain before barrier

        int4v a[4], b[4];
#pragma unroll
        for (int i = 0; i < 4; ++i) {
            a[i] = *(const int4v*)(fA + i * 16 * BK);
            b[i] = *(const int4v*)(fB + i * 16 * BK);
        }
#pragma unroll
        for (int mi = 0; mi < 4; ++mi)
#pragma unroll
            for (int ni = 0; ni < 4; ++ni)
                acc[mi][ni] = __builtin_amdgcn_mfma_i32_16x16x64_i8(
                    a[mi], b[ni], acc[mi][ni], 0, 0, 0);
        __syncthreads();   // protect LDS before next stage overwrites
    }

    // --- epilogue: C/D layout col=lane&15, row=(lane>>4)*4+reg
    const float isc = *iscale;
#pragma unroll
    for (int ni = 0; ni < 4; ++ni) {
        const int col = n0 + wn + ni * 16 + (lane & 15);
        const float bs = bias[col];
        const float inv = 1.0f / (wscale[col] * isc);   // 1/1024: exact (pow2)
#pragma unroll
        for (int mi = 0; mi < 4; ++mi) {
            const int row0 = m0 + wm + mi * 16 + (lane >> 4) * 4;
#pragma unroll
            for (int r = 0; r < 4; ++r) {
                C[(size_t)(row0 + r) * GN + col] =
                    ((float)acc[mi][ni][r] + bs) * inv;
            }
        }
    }
#undef GLL16
}

extern "C" void kernel_launch(void* const* d_in, const int* in_sizes, int n_in,
                              void* d_out, int out_size, void* d_ws, size_t ws_size,
                              hipStream_t stream) {
    const float* x      = (const float*)d_in[0];  // (4,2048,4096)
    const float* w      = (const float*)d_in[1];  // (4096,4096)
    const float* bias   = (const float*)d_in[2];  // (4096,)
    const float* wscale = (const float*)d_in[3];  // (4096,)
    const float* iscale = (const float*)d_in[4];  // (1,)
    float* out = (float*)d_out;

    signed char* xq = (signed char*)d_ws;                       // 32 MiB
    signed char* wq = xq + (size_t)GM * GK;                     // 16 MiB

    const int n4x = GM * GK / 4;
    quant_x_k<<<n4x / 256, 256, 0, stream>>>((const float4*)x,
                                             (unsigned int*)xq, iscale, n4x);
    const int n4w = GN * GK / 4;
    quant_w_k<<<n4w / 256, 256, 0, stream>>>((const float4*)w,
                                             (unsigned int*)wq, wscale, n4w);

    dim3 grid(GM / BM, GN / BN);   // 64 x 32 = 2048 blocks
    qlinear_gemm_i8<<<grid, 256, 0, stream>>>(xq, wq, bias, wscale, iscale, out);
}

// Round 2
// 404.443 us; speedup vs baseline: 1.0564x; 1.0564x over previous
//
#include <hip/hip_runtime.h>

// Problem constants (fixed by reference): B=4, S=2048, DIN=4096, DOUT=4096
#define GM 8192   // M = B*S
#define GN 4096   // N = DOUT
#define GK 4096   // K = DIN

#define BM 128
#define BN 256
#define BK 64     // bytes of K per tile (i8)

using int4v = __attribute__((ext_vector_type(4))) int;

// ---------------- quantization ----------------
// x_int8 = (int)(x * input_scale)  -- trunc toward zero, like astype(int32)
__global__ __launch_bounds__(256) void quant_x_k(const float4* __restrict__ x,
                                                 unsigned int* __restrict__ xq,
                                                 const float* __restrict__ iscale,
                                                 int n4) {
    int i = blockIdx.x * blockDim.x + threadIdx.x;
    if (i >= n4) return;
    float s = *iscale;
    float4 v = x[i];
    int q0 = (int)(v.x * s);
    int q1 = (int)(v.y * s);
    int q2 = (int)(v.z * s);
    int q3 = (int)(v.w * s);
    unsigned int packed = (unsigned int)(q0 & 0xff)
                        | ((unsigned int)(q1 & 0xff) << 8)
                        | ((unsigned int)(q2 & 0xff) << 16)
                        | ((unsigned int)(q3 & 0xff) << 24);
    xq[i] = packed;
}

// w_int8 = round_half_even(w * wscale[row]) -- rintf under default RNE
__global__ __launch_bounds__(256) void quant_w_k(const float4* __restrict__ w,
                                                 unsigned int* __restrict__ wq,
                                                 const float* __restrict__ wscale,
                                                 int n4) {
    int i = blockIdx.x * blockDim.x + threadIdx.x;
    if (i >= n4) return;
    int row = i >> 10;              // 4096 floats per row / 4 per float4
    float s = wscale[row];
    float4 v = w[i];
    int q0 = (int)rintf(v.x * s);
    int q1 = (int)rintf(v.y * s);
    int q2 = (int)rintf(v.z * s);
    int q3 = (int)rintf(v.w * s);
    unsigned int packed = (unsigned int)(q0 & 0xff)
                        | ((unsigned int)(q1 & 0xff) << 8)
                        | ((unsigned int)(q2 & 0xff) << 16)
                        | ((unsigned int)(q3 & 0xff) << 24);
    wq[i] = packed;
}

// ---------------- int8 GEMM ----------------
// Block tile 128x256, BK=64. 4 waves, each computes 64x128 (4x8 of 16x16x64).
// LDS layout XOR-swizzled: chunk (row,kc) of a tile stored at
//   row*64 + (kc ^ ((row>>1)&3))*16
// so quarter-wave ds_read_b128 hits each 16B bank-quad exactly 2x (free).
// global_load_lds forces LDS dest = base + lane*16, so the swizzle is applied
// by permuting the *global source* chunk per lane: kc = (lane&3)^((lane>>3)&3).
__global__ __launch_bounds__(256, 2) void qlinear_gemm_i8(
    const signed char* __restrict__ Aq,
    const signed char* __restrict__ Bq,
    const float* __restrict__ bias,
    const float* __restrict__ wscale,
    const float* __restrict__ iscale,
    float* __restrict__ C) {
    __shared__ signed char As[BM * BK];   // 8 KiB
    __shared__ signed char Bs[BN * BK];   // 16 KiB

    const int tid  = threadIdx.x;
    const int wave = tid >> 6;
    const int lane = tid & 63;
    const int m0 = blockIdx.x * BM;
    const int n0 = blockIdx.y * BN;
    // wave computes a 64x128 subtile (4x8 of 16x16)
    const int wm = (wave >> 1) * 64;     // {0,64}
    const int wn = (wave & 1) * 128;     // {0,128}

    int4v acc[4][8];
#pragma unroll
    for (int i = 0; i < 4; ++i)
#pragma unroll
        for (int j = 0; j < 8; ++j)
            acc[i][j] = int4v{0, 0, 0, 0};

    // --- staging: swizzled global k-chunk byte offset for this lane
    const int kcl = (((lane & 3) ^ ((lane >> 3) & 3))) * 16;

    // A: 8 segments of 16 rows; wave stages segments {2w, 2w+1}
    const int segA = wave * 2;
    const signed char* gA0 = Aq + (size_t)(m0 + segA * 16 + (lane >> 2)) * GK + kcl;
    signed char* lA0 = As + segA * 1024 + lane * 16;
    // B: 16 segments of 16 rows; wave stages segments {4w .. 4w+3}
    const int segB = wave * 4;
    const signed char* gB0 = Bq + (size_t)(n0 + segB * 16 + (lane >> 2)) * GK + kcl;
    signed char* lB0 = Bs + segB * 1024 + lane * 16;

    // --- LDS fragment read addresses (A-operand layout for 16x16x64 i8:
    // elem[m = lane&15][k = (lane>>4)*16 + j]); swizzled chunk position:
    const int pos = ((lane >> 4) ^ ((lane >> 1) & 3)) * 16;
    const signed char* fA = As + (wm + (lane & 15)) * BK + pos;
    const signed char* fB = Bs + (wn + (lane & 15)) * BK + pos;

#define GLL16(g, l)                                                     \
    __builtin_amdgcn_global_load_lds(                                   \
        (__attribute__((address_space(1))) void*)(void*)(g),            \
        (__attribute__((address_space(3))) void*)(l), 16, 0, 0)

    for (int k0 = 0; k0 < GK; k0 += BK) {
        GLL16(gA0 + k0, lA0);
        GLL16(gA0 + (size_t)16 * GK + k0, lA0 + 1024);
        GLL16(gB0 + k0, lB0);
        GLL16(gB0 + (size_t)16 * GK + k0, lB0 + 1024);
        GLL16(gB0 + (size_t)32 * GK + k0, lB0 + 2048);
        GLL16(gB0 + (size_t)48 * GK + k0, lB0 + 3072);
        __syncthreads();

        int4v a[4], b[8];
#pragma unroll
        for (int i = 0; i < 4; ++i)
            a[i] = *(const int4v*)(fA + i * 16 * BK);
#pragma unroll
        for (int j = 0; j < 8; ++j)
            b[j] = *(const int4v*)(fB + j * 16 * BK);
#pragma unroll
        for (int mi = 0; mi < 4; ++mi)
#pragma unroll
            for (int ni = 0; ni < 8; ++ni)
                acc[mi][ni] = __builtin_amdgcn_mfma_i32_16x16x64_i8(
                    a[mi], b[ni], acc[mi][ni], 0, 0, 0);
        __syncthreads();   // protect LDS before next stage overwrites
    }

    // --- epilogue: C/D layout col=lane&15, row=(lane>>4)*4+reg
    const float isc = *iscale;
#pragma unroll
    for (int ni = 0; ni < 8; ++ni) {
        const int col = n0 + wn + ni * 16 + (lane & 15);
        const float bs = bias[col];
        const float inv = 1.0f / (wscale[col] * isc);   // 1/1024: exact (pow2)
#pragma unroll
        for (int mi = 0; mi < 4; ++mi) {
            const int row0 = m0 + wm + mi * 16 + (lane >> 4) * 4;
#pragma unroll
            for (int r = 0; r < 4; ++r) {
                C[(size_t)(row0 + r) * GN + col] =
                    ((float)acc[mi][ni][r] + bs) * inv;
            }
        }
    }
#undef GLL16
}

extern "C" void kernel_launch(void* const* d_in, const int* in_sizes, int n_in,
                              void* d_out, int out_size, void* d_ws, size_t ws_size,
                              hipStream_t stream) {
    const float* x      = (const float*)d_in[0];  // (4,2048,4096)
    const float* w      = (const float*)d_in[1];  // (4096,4096)
    const float* bias   = (const float*)d_in[2];  // (4096,)
    const float* wscale = (const float*)d_in[3];  // (4096,)
    const float* iscale = (const float*)d_in[4];  // (1,)
    float* out = (float*)d_out;

    signed char* xq = (signed char*)d_ws;                       // 32 MiB
    signed char* wq = xq + (size_t)GM * GK;                     // 16 MiB

    const int n4x = GM * GK / 4;
    quant_x_k<<<n4x / 256, 256, 0, stream>>>((const float4*)x,
                                             (unsigned int*)xq, iscale, n4x);
    const int n4w = GN * GK / 4;
    quant_w_k<<<n4w / 256, 256, 0, stream>>>((const float4*)w,
                                             (unsigned int*)wq, wscale, n4w);

    dim3 grid(GM / BM, GN / BN);   // 64 x 16 = 1024 blocks
    qlinear_gemm_i8<<<grid, 256, 0, stream>>>(xq, wq, bias, wscale, iscale, out);
}